// Round 2
// baseline (837.876 us; speedup 1.0000x reference)
//
#include <hip/hip_runtime.h>
#include <math.h>

#define NN 512
#define FF 64
#define HH 64
#define CC 32
#define KK 50

__device__ __forceinline__ float frcp(float x){ return __builtin_amdgcn_rcpf(x); }
__device__ __forceinline__ float fsilu(float x){ return x * frcp(1.0f + __expf(-x)); }
__device__ __forceinline__ float ftanh(float x){ return 1.0f - 2.0f * frcp(__expf(2.0f*x) + 1.0f); }

__device__ __forceinline__ float bfly_max(float v){
    #pragma unroll
    for (int m = 1; m < 64; m <<= 1) v = fmaxf(v, __shfl_xor(v, m, 64));
    return v;
}
__device__ __forceinline__ float bfly_sum(float v){
    #pragma unroll
    for (int m = 1; m < 64; m <<= 1) v += __shfl_xor(v, m, 64);
    return v;
}

__device__ __forceinline__ float block_max4(float v, float* red, int lane, int wid){
    v = bfly_max(v);
    __syncthreads();
    if (lane == 0) red[wid] = v;
    __syncthreads();
    return fmaxf(fmaxf(red[0], red[1]), fmaxf(red[2], red[3]));
}
__device__ __forceinline__ float block_sum4(float v, float* red, int lane, int wid){
    v = bfly_sum(v);
    __syncthreads();
    if (lane == 0) red[wid] = v;
    __syncthreads();
    return (red[0] + red[1]) + (red[2] + red[3]);
}

// ---------------- kernel 1: per-node projections ----------------
extern "C" __global__ __launch_bounds__(128)
void sake_pre(const float* __restrict__ h,
              const float* __restrict__ W_df_in, const float* __restrict__ b_df_in,
              const float* __restrict__ W_ew,    const float* __restrict__ b_ew,
              const float* __restrict__ W_sa,
              float* __restrict__ AT, float* __restrict__ Cm,
              float* __restrict__ ET, float* __restrict__ Fm,
              float* __restrict__ sa, float* __restrict__ sb)
{
    const int node = blockIdx.x;
    __shared__ float hrow[FF];
    const int t = threadIdx.x;
    if (t < FF) hrow[t] = h[node*FF + t];
    __syncthreads();
    if (t < KK) {
        float a = 0.f, c = b_df_in[t];
        #pragma unroll 1
        for (int f = 0; f < FF; ++f) {
            a += hrow[f] * W_df_in[f*KK + t];
            c += hrow[f] * W_df_in[(FF+f)*KK + t];
        }
        AT[t*NN + node] = a;      // transposed: [k][j]
        Cm[node*KK + t] = c;      // row-major: [i][k], b_df_in folded
    } else if (t < KK + CC) {
        int cc = t - KK;
        float e = 0.f, ff = b_ew[cc];
        #pragma unroll 1
        for (int f = 0; f < FF; ++f) {
            e  += hrow[f] * W_ew[f*CC + cc];
            ff += hrow[f] * W_ew[(FF+f)*CC + cc];
        }
        ET[cc*NN + node] = e;     // transposed: [c][j]
        Fm[node*CC + cc] = ff;    // [i][c], b_ew folded
    } else if (t == KK + CC) {
        float v = 0.f;
        #pragma unroll 1
        for (int f = 0; f < FF; ++f) v += hrow[f] * W_sa[f];
        sa[node] = v;
    } else if (t == KK + CC + 1) {
        float v = 0.f;
        #pragma unroll 1
        for (int f = 0; f < FF; ++f) v += hrow[f] * W_sa[FF + f];
        sb[node] = v;
    }
}

// ---------------- kernel 2: fused per-row-i main kernel ----------------
extern "C" __global__ __launch_bounds__(256, 4)
void sake_main(const float* __restrict__ h, const float* __restrict__ x,
               const float* __restrict__ W_df1, const float* __restrict__ b_df1,
               const float* __restrict__ W_df2, const float* __restrict__ b_df2,
               const float* __restrict__ W_ew,
               const float* __restrict__ W_pn1, const float* __restrict__ b_pn1,
               const float* __restrict__ W_pn2, const float* __restrict__ b_pn2,
               const float* __restrict__ W_nm1, const float* __restrict__ b_nm1,
               const float* __restrict__ W_nm2, const float* __restrict__ b_nm2,
               const float* __restrict__ W_cm1, const float* __restrict__ b_cm1,
               const float* __restrict__ W_cm2, const float* __restrict__ b_cm2,
               const float* __restrict__ AT, const float* __restrict__ Cm,
               const float* __restrict__ ET, const float* __restrict__ Fm,
               const float* __restrict__ sa, const float* __restrict__ sb,
               float* __restrict__ out)
{
    extern __shared__ float slice[];   // 256 threads * 64 floats, XOR-swizzled private slices
    __shared__ float red[4];
    __shared__ float sAccX[4][96];
    __shared__ float sAccH[4][64];
    __shared__ float sAccN[4][3];
    __shared__ float xatt_f[96];
    __shared__ float heagg_f[64];
    __shared__ float xnew_f[3];
    __shared__ float xan_s[32];
    __shared__ float pn1_s[64];
    __shared__ float nm1_s[64];
    __shared__ float node_in[192];

    const int i    = blockIdx.x;
    const int tid  = threadIdx.x;
    const int lane = tid & 63;
    const int wid  = tid >> 6;

    const float xi0 = x[i*3+0], xi1 = x[i*3+1], xi2 = x[i*3+2];
    const float sbi = sb[i];

    // ---------- phase A: softmax normalizers over j ----------
    float dx[2][3], dist[2], sval[2];
    #pragma unroll
    for (int u = 0; u < 2; ++u) {
        const int j = tid + u*256;
        float a0 = x[j*3+0]-xi0, a1 = x[j*3+1]-xi1, a2 = x[j*3+2]-xi2;
        dx[u][0]=a0; dx[u][1]=a1; dx[u][2]=a2;
        float d2 = a0*a0 + a1*a1 + a2*a2;
        dist[u] = sqrtf(d2 + 1e-14f);
        sval[u] = fsilu(sa[j] + sbi);
    }
    const float dmax = block_max4(fmaxf(dist[0], dist[1]), red, lane, wid);
    const float dsum = block_sum4(__expf(dist[0]-dmax) + __expf(dist[1]-dmax), red, lane, wid);
    const float smax = block_max4(fmaxf(sval[0], sval[1]), red, lane, wid);
    const float ssum = block_sum4(__expf(sval[0]-smax) + __expf(sval[1]-smax), red, lane, wid);
    const float inv_ds = frcp(dsum * ssum);
    const float p0 = __expf((dist[0]-dmax) + (sval[0]-smax)) * inv_ds;  // sem*spa product
    const float p1 = __expf((dist[1]-dmax) + (sval[1]-smax)) * inv_ds;
    const float pmax = block_max4(fmaxf(p0, p1), red, lane, wid);
    const float t0 = __expf(p0 - pmax), t1 = __expf(p1 - pmax);
    const float tsum = block_sum4(t0 + t1, red, lane, wid);
    const float inv_tsum = frcp(tsum);

    // ---------- phase B: per-pair MLP chain + j-reductions ----------
    float stashX0 = 0.f, stashX1 = 0.f, stashH = 0.f, stashN = 0.f;
    const int swz = tid & 31;
    float* myslice = slice + tid*64;

    #pragma unroll
    for (int u = 0; u < 2; ++u) {
        const int j = tid + u*256;
        const float dj = dist[u];
        const float attw = (u == 0 ? t0 : t1) * inv_tsum;

        // layer 1: he1 = silu( (A_j + C_i) * rbf(dist) @ W_df1 + b_df1 )
        float acc1[HH];
        #pragma unroll
        for (int n = 0; n < HH; ++n) acc1[n] = b_df1[n];
        #pragma unroll 2
        for (int k = 0; k < KK; ++k) {
            float mu = (5.0f/49.0f) * (float)k;
            float dd = dj - mu;
            float v = (AT[k*NN + j] + Cm[i*KK + k]) * __expf(-10.0f*dd*dd);
            const float* Wr = W_df1 + k*HH;
            #pragma unroll
            for (int n = 0; n < HH; ++n) acc1[n] += v * Wr[n];
        }
        #pragma unroll
        for (int n = 0; n < HH; ++n) myslice[n ^ swz] = fsilu(acc1[n]);   // he1 -> slice

        // layer 2: he = he1 @ W_df2 + b_df2
        float acc2[HH];
        #pragma unroll
        for (int n = 0; n < HH; ++n) acc2[n] = b_df2[n];
        #pragma unroll 2
        for (int k = 0; k < HH; ++k) {
            float v = myslice[k ^ swz];
            const float* Wr = W_df2 + k*HH;
            #pragma unroll
            for (int n = 0; n < HH; ++n) acc2[n] += v * Wr[n];
        }
        #pragma unroll
        for (int n = 0; n < HH; ++n) myslice[n ^ swz] = acc2[n];          // he -> slice

        // he_agg contribution (total_att * he), wave butterfly + stash
        #pragma unroll
        for (int n = 0; n < HH; ++n) {
            float v = bfly_sum(attw * acc2[n]);
            if (lane == n) stashH += v;
        }

        // coord MLP: coord_w = silu(he @ W_cm1 + b_cm1) @ W_cm2 + b_cm2
        float accM[HH];
        #pragma unroll
        for (int m = 0; m < HH; ++m) accM[m] = b_cm1[m];
        #pragma unroll 2
        for (int n = 0; n < HH; ++n) {
            float v = myslice[n ^ swz];
            const float* Wm = W_cm1 + n*HH;
            #pragma unroll
            for (int m = 0; m < HH; ++m) accM[m] += v * Wm[m];
        }
        float coordw = b_cm2[0];
        #pragma unroll
        for (int m = 0; m < HH; ++m) coordw += fsilu(accM[m]) * W_cm2[m];

        // edge weights: w_edge = tanh(E_j + F_i + he @ W_ew[128:192])
        float accE[CC];
        #pragma unroll
        for (int c = 0; c < CC; ++c) accE[c] = Fm[i*CC + c];
        #pragma unroll 2
        for (int n = 0; n < HH; ++n) {
            float v = myslice[n ^ swz];
            const float* We = W_ew + (128 + n)*CC;
            #pragma unroll
            for (int c = 0; c < CC; ++c) accE[c] += v * We[c];
        }

        // x_att outer-product reduction over j
        float d2v  = dx[u][0]*dx[u][0] + dx[u][1]*dx[u][1] + dx[u][2]*dx[u][2];
        float invd = frcp(d2v + 1e-5f);
        float xd0 = dx[u][0]*invd, xd1 = dx[u][1]*invd, xd2 = dx[u][2]*invd;
        #pragma unroll
        for (int c = 0; c < CC; ++c) {
            float wec = ftanh(accE[c] + ET[c*NN + j]);
            float vv[3] = { wec*xd0, wec*xd1, wec*xd2 };
            #pragma unroll
            for (int d = 0; d < 3; ++d) {
                float v = bfly_sum(vv[d]);
                int combo = c*3 + d;
                if (combo < 64) { if (lane == combo)      stashX0 += v; }
                else            { if (lane == combo - 64) stashX1 += v; }
            }
        }

        // x_new contribution: sum_j dx * coord_w
        #pragma unroll
        for (int d = 0; d < 3; ++d) {
            float v = bfly_sum(dx[u][d] * coordw);
            if (lane == d) stashN += v;
        }
    }

    __syncthreads();
    sAccX[wid][lane] = stashX0;
    if (lane < 32) sAccX[wid][64 + lane] = stashX1;
    sAccH[wid][lane] = stashH;
    if (lane < 3) sAccN[wid][lane] = stashN;
    __syncthreads();

    if (tid < 96)  xatt_f[tid] = (sAccX[0][tid]+sAccX[1][tid]) + (sAccX[2][tid]+sAccX[3][tid]);
    if (tid >= 128 && tid < 192) {
        int n = tid - 128;
        heagg_f[n] = (sAccH[0][n]+sAccH[1][n]) + (sAccH[2][n]+sAccH[3][n]);
    }
    if (tid >= 224 && tid < 227) {
        int d = tid - 224;
        xnew_f[d] = (sAccN[0][d]+sAccN[1][d]) + (sAccN[2][d]+sAccN[3][d]);
    }
    __syncthreads();

    if (tid < 32) {
        float a = xatt_f[tid*3+0], b = xatt_f[tid*3+1], c = xatt_f[tid*3+2];
        xan_s[tid] = sqrtf(a*a + b*b + c*c + 1e-14f);
    }
    __syncthreads();

    if (tid < 64) {
        float acc = b_pn1[tid];
        #pragma unroll 1
        for (int c = 0; c < CC; ++c) acc += xan_s[c] * W_pn1[c*HH + tid];
        pn1_s[tid] = fsilu(acc);
    }
    __syncthreads();
    if (tid < 64) {
        float acc = b_pn2[tid];
        #pragma unroll 1
        for (int k = 0; k < HH; ++k) acc += pn1_s[k] * W_pn2[k*HH + tid];
        node_in[128 + tid] = acc;              // norm_emb
        node_in[tid]       = h[i*FF + tid];    // h
        node_in[64 + tid]  = heagg_f[tid];     // he_agg
    }
    __syncthreads();
    if (tid < 64) {
        float acc = b_nm1[tid];
        #pragma unroll 1
        for (int k = 0; k < 192; ++k) acc += node_in[k] * W_nm1[k*HH + tid];
        nm1_s[tid] = fsilu(acc);
    }
    __syncthreads();
    if (tid < 64) {
        float acc = b_nm2[tid];
        #pragma unroll 1
        for (int k = 0; k < HH; ++k) acc += nm1_s[k] * W_nm2[k*HH + tid];
        out[i*HH + tid] = acc;                 // h_new
    }
    if (tid >= 64 && tid < 67) {
        int d = tid - 64;
        out[NN*HH + i*3 + d] = xnew_f[d] + x[i*3 + d];   // x_new
    }
}

extern "C" void kernel_launch(void* const* d_in, const int* in_sizes, int n_in,
                              void* d_out, int out_size, void* d_ws, size_t ws_size,
                              hipStream_t stream)
{
    const float* h       = (const float*)d_in[0];
    const float* x       = (const float*)d_in[1];
    const float* W_df_in = (const float*)d_in[2];
    const float* b_df_in = (const float*)d_in[3];
    const float* W_df1   = (const float*)d_in[4];
    const float* b_df1   = (const float*)d_in[5];
    const float* W_df2   = (const float*)d_in[6];
    const float* b_df2   = (const float*)d_in[7];
    const float* W_ew    = (const float*)d_in[8];
    const float* b_ew    = (const float*)d_in[9];
    const float* W_pn1   = (const float*)d_in[10];
    const float* b_pn1   = (const float*)d_in[11];
    const float* W_pn2   = (const float*)d_in[12];
    const float* b_pn2   = (const float*)d_in[13];
    const float* W_nm1   = (const float*)d_in[14];
    const float* b_nm1   = (const float*)d_in[15];
    const float* W_nm2   = (const float*)d_in[16];
    const float* b_nm2   = (const float*)d_in[17];
    const float* W_cm1   = (const float*)d_in[18];
    const float* b_cm1   = (const float*)d_in[19];
    const float* W_cm2   = (const float*)d_in[20];
    const float* b_cm2   = (const float*)d_in[21];
    const float* W_sa    = (const float*)d_in[22];
    float* out = (float*)d_out;

    float* ws = (float*)d_ws;
    float* AT = ws;               // 50*512
    float* Cm = AT + KK*NN;       // 512*50
    float* ET = Cm + NN*KK;       // 32*512
    float* Fm = ET + CC*NN;       // 512*32
    float* sa = Fm + NN*CC;       // 512
    float* sb = sa + NN;          // 512

    (void)hipFuncSetAttribute((const void*)sake_main,
        hipFuncAttributeMaxDynamicSharedMemorySize, 256*64*4);

    sake_pre<<<NN, 128, 0, stream>>>(h, W_df_in, b_df_in, W_ew, b_ew, W_sa,
                                     AT, Cm, ET, Fm, sa, sb);
    sake_main<<<NN, 256, 256*64*4, stream>>>(h, x,
        W_df1, b_df1, W_df2, b_df2, W_ew,
        W_pn1, b_pn1, W_pn2, b_pn2, W_nm1, b_nm1, W_nm2, b_nm2,
        W_cm1, b_cm1, W_cm2, b_cm2,
        AT, Cm, ET, Fm, sa, sb, out);
}

// Round 3
// 662.325 us; speedup vs baseline: 1.2651x; 1.2651x over previous
//
#include <hip/hip_runtime.h>
#include <math.h>

#define NN 512
#define FF 64
#define HH 64
#define CC 32
#define KK 50

__device__ __forceinline__ float frcp(float x){ return __builtin_amdgcn_rcpf(x); }
__device__ __forceinline__ float fsilu(float x){ return x * frcp(1.0f + __expf(-x)); }
__device__ __forceinline__ float ftanh(float x){ return 1.0f - 2.0f * frcp(__expf(2.0f*x) + 1.0f); }

__device__ __forceinline__ float bfly_max(float v){
    #pragma unroll
    for (int m = 1; m < 64; m <<= 1) v = fmaxf(v, __shfl_xor(v, m, 64));
    return v;
}
__device__ __forceinline__ float bfly_sum(float v){
    #pragma unroll
    for (int m = 1; m < 64; m <<= 1) v += __shfl_xor(v, m, 64);
    return v;
}

__device__ __forceinline__ float block_max4(float v, float* red, int lane, int wid){
    v = bfly_max(v);
    __syncthreads();
    if (lane == 0) red[wid] = v;
    __syncthreads();
    return fmaxf(fmaxf(red[0], red[1]), fmaxf(red[2], red[3]));
}
__device__ __forceinline__ float block_sum4(float v, float* red, int lane, int wid){
    v = bfly_sum(v);
    __syncthreads();
    if (lane == 0) red[wid] = v;
    __syncthreads();
    return (red[0] + red[1]) + (red[2] + red[3]);
}

// ---------------- kernel 1: per-node projections ----------------
extern "C" __global__ __launch_bounds__(128)
void sake_pre(const float* __restrict__ h,
              const float* __restrict__ W_df_in, const float* __restrict__ b_df_in,
              const float* __restrict__ W_ew,    const float* __restrict__ b_ew,
              const float* __restrict__ W_sa,
              float* __restrict__ AT, float* __restrict__ Cm,
              float* __restrict__ ET, float* __restrict__ Fm,
              float* __restrict__ sa, float* __restrict__ sb)
{
    const int node = blockIdx.x;
    __shared__ float hrow[FF];
    const int t = threadIdx.x;
    if (t < FF) hrow[t] = h[node*FF + t];
    __syncthreads();
    if (t < KK) {
        float a = 0.f, c = b_df_in[t];
        #pragma unroll 1
        for (int f = 0; f < FF; ++f) {
            a += hrow[f] * W_df_in[f*KK + t];
            c += hrow[f] * W_df_in[(FF+f)*KK + t];
        }
        AT[t*NN + node] = a;      // transposed: [k][j]
        Cm[node*KK + t] = c;      // row-major: [i][k], b_df_in folded
    } else if (t < KK + CC) {
        int cc = t - KK;
        float e = 0.f, ff = b_ew[cc];
        #pragma unroll 1
        for (int f = 0; f < FF; ++f) {
            e  += hrow[f] * W_ew[f*CC + cc];
            ff += hrow[f] * W_ew[(FF+f)*CC + cc];
        }
        ET[cc*NN + node] = e;     // transposed: [c][j]
        Fm[node*CC + cc] = ff;    // [i][c], b_ew folded
    } else if (t == KK + CC) {
        float v = 0.f;
        #pragma unroll 1
        for (int f = 0; f < FF; ++f) v += hrow[f] * W_sa[f];
        sa[node] = v;
    } else if (t == KK + CC + 1) {
        float v = 0.f;
        #pragma unroll 1
        for (int f = 0; f < FF; ++f) v += hrow[f] * W_sa[FF + f];
        sb[node] = v;
    }
}

// ---------------- kernel 2: fused per-row-i main kernel ----------------
// (256,2): VGPR cap 256. The 64KiB dynamic LDS slice already limits us to
// 2 blocks/CU = 2 waves/SIMD, so this costs no occupancy vs (256,4) --
// but (256,4)'s 128-VGPR cap forced the accumulator arrays to scratch
// (round-2 counters: VGPR=64, 245MB scratch writes, VALUBusy 10%).
extern "C" __global__ __launch_bounds__(256, 2)
void sake_main(const float* __restrict__ h, const float* __restrict__ x,
               const float* __restrict__ W_df1, const float* __restrict__ b_df1,
               const float* __restrict__ W_df2, const float* __restrict__ b_df2,
               const float* __restrict__ W_ew,
               const float* __restrict__ W_pn1, const float* __restrict__ b_pn1,
               const float* __restrict__ W_pn2, const float* __restrict__ b_pn2,
               const float* __restrict__ W_nm1, const float* __restrict__ b_nm1,
               const float* __restrict__ W_nm2, const float* __restrict__ b_nm2,
               const float* __restrict__ W_cm1, const float* __restrict__ b_cm1,
               const float* __restrict__ W_cm2, const float* __restrict__ b_cm2,
               const float* __restrict__ AT, const float* __restrict__ Cm,
               const float* __restrict__ ET, const float* __restrict__ Fm,
               const float* __restrict__ sa, const float* __restrict__ sb,
               float* __restrict__ out)
{
    extern __shared__ float slice[];   // 256 threads * 64 floats, XOR-swizzled private slices
    __shared__ float red[4];
    __shared__ float sAccX[4][96];
    __shared__ float sAccH[4][64];
    __shared__ float sAccN[4][3];
    __shared__ float xatt_f[96];
    __shared__ float heagg_f[64];
    __shared__ float xnew_f[3];
    __shared__ float xan_s[32];
    __shared__ float pn1_s[64];
    __shared__ float nm1_s[64];
    __shared__ float node_in[192];

    const int i    = blockIdx.x;
    const int tid  = threadIdx.x;
    const int lane = tid & 63;
    const int wid  = tid >> 6;

    const float xi0 = x[i*3+0], xi1 = x[i*3+1], xi2 = x[i*3+2];
    const float sbi = sb[i];

    // ---------- phase A: softmax normalizers over j ----------
    float dx[2][3], dist[2], sval[2];
    #pragma unroll
    for (int u = 0; u < 2; ++u) {
        const int j = tid + u*256;
        float a0 = x[j*3+0]-xi0, a1 = x[j*3+1]-xi1, a2 = x[j*3+2]-xi2;
        dx[u][0]=a0; dx[u][1]=a1; dx[u][2]=a2;
        float d2 = a0*a0 + a1*a1 + a2*a2;
        dist[u] = sqrtf(d2 + 1e-14f);
        sval[u] = fsilu(sa[j] + sbi);
    }
    const float dmax = block_max4(fmaxf(dist[0], dist[1]), red, lane, wid);
    const float dsum = block_sum4(__expf(dist[0]-dmax) + __expf(dist[1]-dmax), red, lane, wid);
    const float smax = block_max4(fmaxf(sval[0], sval[1]), red, lane, wid);
    const float ssum = block_sum4(__expf(sval[0]-smax) + __expf(sval[1]-smax), red, lane, wid);
    const float inv_ds = frcp(dsum * ssum);
    const float p0 = __expf((dist[0]-dmax) + (sval[0]-smax)) * inv_ds;  // sem*spa product
    const float p1 = __expf((dist[1]-dmax) + (sval[1]-smax)) * inv_ds;
    const float pmax = block_max4(fmaxf(p0, p1), red, lane, wid);
    const float t0 = __expf(p0 - pmax), t1 = __expf(p1 - pmax);
    const float tsum = block_sum4(t0 + t1, red, lane, wid);
    const float inv_tsum = frcp(tsum);

    // ---------- phase B: per-pair MLP chain + j-reductions ----------
    float stashX0 = 0.f, stashX1 = 0.f, stashH = 0.f, stashN = 0.f;
    const int swz = tid & 31;
    float* myslice = slice + tid*64;

    #pragma unroll
    for (int u = 0; u < 2; ++u) {
        const int j = tid + u*256;
        const float dj = dist[u];
        const float attw = (u == 0 ? t0 : t1) * inv_tsum;

        // layer 1: he1 = silu( (A_j + C_i) * rbf(dist) @ W_df1 + b_df1 )
        float acc1[HH];
        #pragma unroll
        for (int n = 0; n < HH; ++n) acc1[n] = b_df1[n];
        #pragma unroll 2
        for (int k = 0; k < KK; ++k) {
            float mu = (5.0f/49.0f) * (float)k;
            float dd = dj - mu;
            float v = (AT[k*NN + j] + Cm[i*KK + k]) * __expf(-10.0f*dd*dd);
            const float* Wr = W_df1 + k*HH;
            #pragma unroll
            for (int n = 0; n < HH; ++n) acc1[n] += v * Wr[n];
        }
        #pragma unroll
        for (int n = 0; n < HH; ++n) myslice[n ^ swz] = fsilu(acc1[n]);   // he1 -> slice

        // layer 2: he = he1 @ W_df2 + b_df2
        float acc2[HH];
        #pragma unroll
        for (int n = 0; n < HH; ++n) acc2[n] = b_df2[n];
        #pragma unroll 2
        for (int k = 0; k < HH; ++k) {
            float v = myslice[k ^ swz];
            const float* Wr = W_df2 + k*HH;
            #pragma unroll
            for (int n = 0; n < HH; ++n) acc2[n] += v * Wr[n];
        }
        #pragma unroll
        for (int n = 0; n < HH; ++n) myslice[n ^ swz] = acc2[n];          // he -> slice

        // he_agg contribution (total_att * he), wave butterfly + stash
        #pragma unroll
        for (int n = 0; n < HH; ++n) {
            float v = bfly_sum(attw * acc2[n]);
            if (lane == n) stashH += v;
        }

        // coord MLP: coord_w = silu(he @ W_cm1 + b_cm1) @ W_cm2 + b_cm2
        float accM[HH];
        #pragma unroll
        for (int m = 0; m < HH; ++m) accM[m] = b_cm1[m];
        #pragma unroll 2
        for (int n = 0; n < HH; ++n) {
            float v = myslice[n ^ swz];
            const float* Wm = W_cm1 + n*HH;
            #pragma unroll
            for (int m = 0; m < HH; ++m) accM[m] += v * Wm[m];
        }
        float coordw = b_cm2[0];
        #pragma unroll
        for (int m = 0; m < HH; ++m) coordw += fsilu(accM[m]) * W_cm2[m];

        // edge weights: w_edge = tanh(E_j + F_i + he @ W_ew[128:192])
        float accE[CC];
        #pragma unroll
        for (int c = 0; c < CC; ++c) accE[c] = Fm[i*CC + c];
        #pragma unroll 2
        for (int n = 0; n < HH; ++n) {
            float v = myslice[n ^ swz];
            const float* We = W_ew + (128 + n)*CC;
            #pragma unroll
            for (int c = 0; c < CC; ++c) accE[c] += v * We[c];
        }

        // x_att outer-product reduction over j
        float d2v  = dx[u][0]*dx[u][0] + dx[u][1]*dx[u][1] + dx[u][2]*dx[u][2];
        float invd = frcp(d2v + 1e-5f);
        float xd0 = dx[u][0]*invd, xd1 = dx[u][1]*invd, xd2 = dx[u][2]*invd;
        #pragma unroll
        for (int c = 0; c < CC; ++c) {
            float wec = ftanh(accE[c] + ET[c*NN + j]);
            float vv[3] = { wec*xd0, wec*xd1, wec*xd2 };
            #pragma unroll
            for (int d = 0; d < 3; ++d) {
                float v = bfly_sum(vv[d]);
                int combo = c*3 + d;
                if (combo < 64) { if (lane == combo)      stashX0 += v; }
                else            { if (lane == combo - 64) stashX1 += v; }
            }
        }

        // x_new contribution: sum_j dx * coord_w
        #pragma unroll
        for (int d = 0; d < 3; ++d) {
            float v = bfly_sum(dx[u][d] * coordw);
            if (lane == d) stashN += v;
        }
    }

    __syncthreads();
    sAccX[wid][lane] = stashX0;
    if (lane < 32) sAccX[wid][64 + lane] = stashX1;
    sAccH[wid][lane] = stashH;
    if (lane < 3) sAccN[wid][lane] = stashN;
    __syncthreads();

    if (tid < 96)  xatt_f[tid] = (sAccX[0][tid]+sAccX[1][tid]) + (sAccX[2][tid]+sAccX[3][tid]);
    if (tid >= 128 && tid < 192) {
        int n = tid - 128;
        heagg_f[n] = (sAccH[0][n]+sAccH[1][n]) + (sAccH[2][n]+sAccH[3][n]);
    }
    if (tid >= 224 && tid < 227) {
        int d = tid - 224;
        xnew_f[d] = (sAccN[0][d]+sAccN[1][d]) + (sAccN[2][d]+sAccN[3][d]);
    }
    __syncthreads();

    if (tid < 32) {
        float a = xatt_f[tid*3+0], b = xatt_f[tid*3+1], c = xatt_f[tid*3+2];
        xan_s[tid] = sqrtf(a*a + b*b + c*c + 1e-14f);
    }
    __syncthreads();

    if (tid < 64) {
        float acc = b_pn1[tid];
        #pragma unroll 1
        for (int c = 0; c < CC; ++c) acc += xan_s[c] * W_pn1[c*HH + tid];
        pn1_s[tid] = fsilu(acc);
    }
    __syncthreads();
    if (tid < 64) {
        float acc = b_pn2[tid];
        #pragma unroll 1
        for (int k = 0; k < HH; ++k) acc += pn1_s[k] * W_pn2[k*HH + tid];
        node_in[128 + tid] = acc;              // norm_emb
        node_in[tid]       = h[i*FF + tid];    // h
        node_in[64 + tid]  = heagg_f[tid];     // he_agg
    }
    __syncthreads();
    if (tid < 64) {
        float acc = b_nm1[tid];
        #pragma unroll 1
        for (int k = 0; k < 192; ++k) acc += node_in[k] * W_nm1[k*HH + tid];
        nm1_s[tid] = fsilu(acc);
    }
    __syncthreads();
    if (tid < 64) {
        float acc = b_nm2[tid];
        #pragma unroll 1
        for (int k = 0; k < HH; ++k) acc += nm1_s[k] * W_nm2[k*HH + tid];
        out[i*HH + tid] = acc;                 // h_new
    }
    if (tid >= 64 && tid < 67) {
        int d = tid - 64;
        out[NN*HH + i*3 + d] = xnew_f[d] + x[i*3 + d];   // x_new
    }
}

extern "C" void kernel_launch(void* const* d_in, const int* in_sizes, int n_in,
                              void* d_out, int out_size, void* d_ws, size_t ws_size,
                              hipStream_t stream)
{
    const float* h       = (const float*)d_in[0];
    const float* x       = (const float*)d_in[1];
    const float* W_df_in = (const float*)d_in[2];
    const float* b_df_in = (const float*)d_in[3];
    const float* W_df1   = (const float*)d_in[4];
    const float* b_df1   = (const float*)d_in[5];
    const float* W_df2   = (const float*)d_in[6];
    const float* b_df2   = (const float*)d_in[7];
    const float* W_ew    = (const float*)d_in[8];
    const float* b_ew    = (const float*)d_in[9];
    const float* W_pn1   = (const float*)d_in[10];
    const float* b_pn1   = (const float*)d_in[11];
    const float* W_pn2   = (const float*)d_in[12];
    const float* b_pn2   = (const float*)d_in[13];
    const float* W_nm1   = (const float*)d_in[14];
    const float* b_nm1   = (const float*)d_in[15];
    const float* W_nm2   = (const float*)d_in[16];
    const float* b_nm2   = (const float*)d_in[17];
    const float* W_cm1   = (const float*)d_in[18];
    const float* b_cm1   = (const float*)d_in[19];
    const float* W_cm2   = (const float*)d_in[20];
    const float* b_cm2   = (const float*)d_in[21];
    const float* W_sa    = (const float*)d_in[22];
    float* out = (float*)d_out;

    float* ws = (float*)d_ws;
    float* AT = ws;               // 50*512
    float* Cm = AT + KK*NN;       // 512*50
    float* ET = Cm + NN*KK;       // 32*512
    float* Fm = ET + CC*NN;       // 512*32
    float* sa = Fm + NN*CC;       // 512
    float* sb = sa + NN;          // 512

    (void)hipFuncSetAttribute((const void*)sake_main,
        hipFuncAttributeMaxDynamicSharedMemorySize, 256*64*4);

    sake_pre<<<NN, 128, 0, stream>>>(h, W_df_in, b_df_in, W_ew, b_ew, W_sa,
                                     AT, Cm, ET, Fm, sa, sb);
    sake_main<<<NN, 256, 256*64*4, stream>>>(h, x,
        W_df1, b_df1, W_df2, b_df2, W_ew,
        W_pn1, b_pn1, W_pn2, b_pn2, W_nm1, b_nm1, W_nm2, b_nm2,
        W_cm1, b_cm1, W_cm2, b_cm2,
        AT, Cm, ET, Fm, sa, sb, out);
}